// Round 5
// baseline (344.461 us; speedup 1.0000x reference)
//
#include <hip/hip_runtime.h>
#include <stdint.h>

#define BATCH 32
#define H 512
#define W 512
#define NACC 16
#define TH 16              // center rows per tile
#define HALO 9             // need M_1..M_9 only
#define RH (TH + 2*HALO)   // 34 rows incl. halo
#define NT 512
#define NW (NT/64)         // 8 waves
#define NTILE (H/TH)       // 32
#define NBLK (NTILE*BATCH) // 1024 blocks = 4/CU

// acc[b*NACC + k]:
//  0: sum(p*g)  1: sum(p)  2: sum(g)
//  3: cnt_pe 4: cnt_pm 5: cnt_pj  6: cnt_ge 7: cnt_gm 8: cnt_gj
//  9: int_e 10: int_m 11: int_j
// 12: dsum_p2g 13: cnt_p2g 14: dsum_g2p 15: cnt_g2p
// acc[BATCH*NACC] (as uint): ticket counter

__device__ __forceinline__ float ld_acc(float* p) {
    // L2-coherent read (RMW, bypasses L1) — safe cross-XCD after release fence
    return atomicAdd(p, 0.0f);
}

__global__ __launch_bounds__(NT, 8) void fused_kernel(
    const float* __restrict__ pred, const float* __restrict__ gt,
    float* __restrict__ acc, float* __restrict__ out)
{
    __shared__ uint64_t Mp[2][RH][8];    // pred mask, double-buffered
    __shared__ uint64_t Mg[2][RH][8];    // gt mask
    __shared__ float    EC[2][TH];       // pred colsums at cols 255|256
    __shared__ float    red[NW][16];
    __shared__ unsigned int isLast;

    // XCD-aware swizzle: 4 row-adjacent tiles share an XCD's L2
    int fid = blockIdx.x;
    int b   = fid >> 5;
    int t5  = fid & 31;
    int tile = ((t5 & 7) << 2) | (t5 >> 3);

    const float* pimg = pred + (size_t)b * H * W;
    const float* gimg = gt   + (size_t)b * H * W;
    int y0 = tile * TH;
    int tid = threadIdx.x, lane = tid & 63, wid = tid >> 6;

    float v0 = 0.f, v1 = 0.f;   // sum(p*g), sum(p) — folded into phase 1

    // ---- Phase 1: ballot masks, rows y0-9 .. y0+24 (272 tasks, x2 unrolled)
    for (int s = wid; s < RH * 8; s += 2 * NW) {
        int rA = s >> 3, segA = s & 7;
        int rB = (s + NW) >> 3, segB = (s + NW) & 7;
        int ryA = y0 - HALO + rA, ryB = y0 - HALO + rB;
        float vpA = 0.f, vgA = 0.f, vpB = 0.f, vgB = 0.f;
        if ((unsigned)ryA < (unsigned)H) {
            int idx = ryA * W + segA * 64 + lane;
            vpA = pimg[idx]; vgA = gimg[idx];
        }
        if ((unsigned)ryB < (unsigned)H) {
            int idx = ryB * W + segB * 64 + lane;
            vpB = pimg[idx]; vgB = gimg[idx];
        }
        unsigned long long mpA = __ballot(vpA > 0.5f);
        unsigned long long mgA = __ballot(vgA > 0.5f);
        unsigned long long mpB = __ballot(vpB > 0.5f);
        unsigned long long mgB = __ballot(vgB > 0.5f);
        if (lane == 0) {
            Mp[0][rA][segA] = mpA; Mg[0][rA][segA] = mgA;
            Mp[0][rB][segB] = mpB; Mg[0][rB][segB] = mgB;
        }
        if (rA >= HALO && rA < HALO + TH) { v1 += vpA; v0 += (vgA > 0.5f) ? vpA : 0.f; }
        if (rB >= HALO && rB < HALO + TH) { v1 += vpB; v0 += (vgB > 0.5f) ? vpB : 0.f; }
    }
    // pred edge colsums (cols 255,256) for the cross-wave stencil halo
    if (tid < 2 * TH) {
        int c = tid >> 4, r = tid & (TH - 1);
        int y = y0 + r, col = 255 + c;
        float sum = (y > 0     ? pimg[(size_t)(y - 1) * W + col] : 0.f)
                  +              pimg[(size_t)y * W + col]
                  + (y < H - 1 ? pimg[(size_t)(y + 1) * W + col] : 0.f);
        EC[c][r] = sum;
    }
    __syncthreads();

    // ---- Target bits for distance (center 16 rows = 128 words, tid<128)
    uint64_t Tp = 0ULL, Tg = 0ULL;
    if (tid < TH * 8) {
        int r = HALO + (tid >> 3), w = tid & 7;
        Tp = Mp[0][r][w]; Tg = Mg[0][r][w];
    }
    int dcnt_p = __popcll(Tp), dcnt_g = __popcll(Tg);
    int dsum_p = dcnt_p, dsum_g = dcnt_g;   // a=0 baseline (dist >= 1)

    // ---- Stencil: pred via floats (rolling rows), gt via bit popcounts
    float c3=0,c4=0,c5=0,c6=0,c7=0,c8=0,c9=0,c10=0,c11=0;
    {
        int qi = tid & 127, h = tid >> 7;     // h in 0..3, 4 rows each
        int x4 = qi * 4;
        int wdx = qi >> 4;                    // word for this quad
        int ss = (qi & 15) * 4;               // bit offset of x4 in word
        int ys = y0 + h * 4;

        auto win6 = [&](int rb) -> uint32_t {
            const uint64_t* row = Mg[0][rb];
            uint64_t bm = row[wdx];
            if (ss == 0) {
                uint64_t lo = wdx ? row[wdx - 1] : 0ULL;
                return (uint32_t)(((bm << 1) | (lo >> 63)) & 0x3FULL);
            }
            uint32_t v = (uint32_t)((bm >> (ss - 1)) & 0x3FULL);
            if (ss == 60) {
                uint64_t hi = (wdx < 7) ? row[wdx + 1] : 0ULL;
                v |= ((uint32_t)hi & 1u) << 5;
            }
            return v;
        };

        int rb0 = h * 4 + HALO - 1;           // bit-row of (ys-1)
        uint32_t wU = win6(rb0), wM = win6(rb0 + 1);

        float4 pm4, pc4;
        {
            bool hm = ys > 0;
            pm4 = hm ? *(const float4*)(pimg + (size_t)(ys - 1) * W + x4)
                     : make_float4(0, 0, 0, 0);
            pc4 = *(const float4*)(pimg + (size_t)ys * W + x4);
        }
        for (int r = 0; r < 4; ++r) {
            int y = ys + r;
            float4 pp4 = (y < H - 1) ? *(const float4*)(pimg + (size_t)(y + 1) * W + x4)
                                     : make_float4(0, 0, 0, 0);
            uint32_t wD = win6(rb0 + 2 + r);
            int ry = h * 4 + r;

            float ps[6];
            ps[1] = pm4.x + pc4.x + pp4.x; ps[2] = pm4.y + pc4.y + pp4.y;
            ps[3] = pm4.z + pc4.z + pp4.z; ps[4] = pm4.w + pc4.w + pp4.w;
            float psl = __shfl_up(ps[4], 1, 64);
            float psr = __shfl_down(ps[1], 1, 64);
            if (lane == 0)  psl = (qi == 0)   ? 0.f : EC[0][ry];
            if (lane == 63) psr = (qi == 127) ? 0.f : EC[1][ry];
            ps[0] = psl; ps[5] = psr;

            float pcv[4] = {pc4.x, pc4.y, pc4.z, pc4.w};
            #pragma unroll
            for (int j = 0; j < 4; ++j) {
                float np = ps[j] + ps[j + 1] + ps[j + 2] - pcv[j];
                bool pon = pcv[j] > 0.5f;
                bool pe  = pon && (np == 1.f);
                bool pmb = pon && (np == 2.f);
                bool pjb = pon && (np > 2.f);
                uint32_t n9 = ((wU >> j) & 7u) | (((wM >> j) & 7u) << 3) | (((wD >> j) & 7u) << 6);
                uint32_t cen = (wM >> (j + 1)) & 1u;
                int ng = __popc(n9) - (int)cen;
                bool gon = cen != 0u;
                bool ge  = gon && (ng == 1);
                bool gmb = gon && (ng == 2);
                bool gjb = gon && (ng > 2);
                c3 += pe;  c4 += pmb;  c5 += pjb;
                c6 += ge;  c7 += gmb;  c8 += gjb;
                c9  += (pe && ge);
                c10 += (pmb && gmb);
                c11 += (pjb && gjb);
            }
            pm4 = pc4; pc4 = pp4; wU = wM; wM = wD;
        }
    }

    // ---- 9 bit-dilation steps (272 active word-tasks); popcount after each
    int cur = 0;
    bool active = tid < RH * 8;
    int rr = tid >> 3, ww = tid & 7;
    int rc = HALO + (tid >> 3), wc = tid & 7;   // center word (tid < 128)
    for (int a = 1; a <= 9; ++a) {
        if (active) {
            uint64_t up, md, dn;
            up = rr ? Mp[cur][rr - 1][ww] : 0ULL;
            md = Mp[cur][rr][ww];
            dn = (rr < RH - 1) ? Mp[cur][rr + 1][ww] : 0ULL;
            uint64_t Xp = up | md | dn;
            up = rr ? Mg[cur][rr - 1][ww] : 0ULL;
            md = Mg[cur][rr][ww];
            dn = (rr < RH - 1) ? Mg[cur][rr + 1][ww] : 0ULL;
            uint64_t Xg = up | md | dn;

            uint32_t lmp = __shfl_up  ((uint32_t)(Xp >> 63), 1, 64);
            uint32_t rlp = __shfl_down((uint32_t)(Xp & 1ULL), 1, 64);
            uint32_t lmg = __shfl_up  ((uint32_t)(Xg >> 63), 1, 64);
            uint32_t rlg = __shfl_down((uint32_t)(Xg & 1ULL), 1, 64);

            uint64_t Yp = Xp | (Xp << 1) | (Xp >> 1);
            uint64_t Yg = Xg | (Xg << 1) | (Xg >> 1);
            if (ww > 0) { Yp |= (uint64_t)(lmp & 1u); Yg |= (uint64_t)(lmg & 1u); }
            if (ww < 7) { Yp |= ((uint64_t)(rlp & 1u)) << 63; Yg |= ((uint64_t)(rlg & 1u)) << 63; }
            Mp[cur ^ 1][rr][ww] = Yp;
            Mg[cur ^ 1][rr][ww] = Yg;
        }
        __syncthreads();
        cur ^= 1;
        if (tid < TH * 8) {
            dsum_p += __popcll(Tp & ~Mg[cur][rc][wc]);  // pred targets vs gt coverage
            dsum_g += __popcll(Tg & ~Mp[cur][rc][wc]);  // gt targets vs pred coverage
        }
    }

    // ---- Reductions
    float vals[16];
    vals[0] = v0; vals[1] = v1; vals[2] = (float)dcnt_g;
    vals[3] = c3; vals[4] = c4; vals[5] = c5;
    vals[6] = c6; vals[7] = c7; vals[8] = c8;
    vals[9] = c9; vals[10] = c10; vals[11] = c11;
    vals[12] = (float)dsum_p; vals[13] = (float)dcnt_p;
    vals[14] = (float)dsum_g; vals[15] = (float)dcnt_g;
    #pragma unroll
    for (int j = 0; j < 16; ++j)
        #pragma unroll
        for (int off = 32; off; off >>= 1)
            vals[j] += __shfl_down(vals[j], off, 64);
    if (lane == 0) {
        #pragma unroll
        for (int j = 0; j < 16; ++j) red[wid][j] = vals[j];
    }
    __syncthreads();
    if (tid < 16) {
        float s = 0.f;
        #pragma unroll
        for (int wv = 0; wv < NW; ++wv) s += red[wv][tid];
        atomicAdd(&acc[b * NACC + tid], s);
    }

    // ---- Last block computes the final scalar (device-scope ticket)
    __threadfence();
    if (tid == 0) {
        unsigned int t = atomicAdd((unsigned int*)&acc[BATCH * NACC], 1u);
        isLast = (t == NBLK - 1) ? 1u : 0u;
    }
    __syncthreads();
    if (isLast && tid < 64) {
        __threadfence();
        int bb = tid;
        float dice = 0.f, sloss = 0.f, med = 0.f;
        if (bb < BATCH) {
            float* a = acc + bb * NACC;
            float av[16];
            #pragma unroll
            for (int j = 0; j < 16; ++j) av[j] = ld_acc(&a[j]);
            float inter = av[0], psum = av[1], gsum = av[2];
            dice = (2.f * inter + 1.f) / (psum + gsum + 1.f);

            float pe = av[3], pm = av[4], pj = av[5];
            float ge = av[6], gm = av[7], gj = av[8];
            float ie = av[9], im = av[10], ij = av[11];
            float e_iou = (ie + 1.f) / (pe + ge - ie + 1.f);
            float m_iou = (im + 1.f) / (pm + gm - im + 1.f);
            float j_iou = (ij + 1.f) / (pj + gj - ij + 1.f);
            float total = ge + gj + gm + 1.f;
            sloss = 1.f - ((ge / total) * e_iou + (gj / total) * j_iou + (gm / total) * m_iou);

            float p2g = av[12] / (av[13] + 1.f);
            float g2p = av[14] / (av[15] + 1.f);
            med = ((p2g + g2p) * 0.5f) / 10.f;
        }
        #pragma unroll
        for (int off = 32; off; off >>= 1) {
            dice  += __shfl_down(dice,  off, 64);
            sloss += __shfl_down(sloss, off, 64);
            med   += __shfl_down(med,   off, 64);
        }
        if (tid == 0) {
            float dice_loss  = 1.f - dice / (float)BATCH;
            float structural = sloss / (float)BATCH;
            float medial     = med / (float)BATCH;
            float avg = (dice_loss + structural + medial) / 3.f;
            float r = dice_loss  / (dice_loss  + 1.f) * avg
                    + structural / (structural + 1.f) * avg
                    + medial     / (medial     + 1.f) * avg;
            out[0] = r;
        }
    }
}

extern "C" void kernel_launch(void* const* d_in, const int* in_sizes, int n_in,
                              void* d_out, int out_size, void* d_ws, size_t ws_size,
                              hipStream_t stream)
{
    const float* pred = (const float*)d_in[0];
    const float* gt   = (const float*)d_in[1];
    float* acc = (float*)d_ws;
    float* out = (float*)d_out;

    hipMemsetAsync(acc, 0, (BATCH * NACC + 1) * sizeof(float), stream);
    fused_kernel<<<dim3(NBLK), NT, 0, stream>>>(pred, gt, acc, out);
}

// Round 6
// 139.456 us; speedup vs baseline: 2.4700x; 2.4700x over previous
//
#include <hip/hip_runtime.h>
#include <stdint.h>

#define BATCH 32
#define H 512
#define W 512
#define NACC 16
#define TH 16              // center rows per tile
#define HALO 9             // need M_1..M_9 only
#define RH (TH + 2*HALO)   // 34 rows incl. halo
#define NT 512
#define NW (NT/64)         // 8 waves
#define NTILE (H/TH)       // 32
#define NBLK (NTILE*BATCH) // 1024 blocks = 4/CU

// part[fid*NACC + k] per-block partials (no atomics, deterministic):
//  0: sum(p*g)  1: sum(p)  2: sum(g)
//  3: cnt_pe 4: cnt_pm 5: cnt_pj  6: cnt_ge 7: cnt_gm 8: cnt_gj
//  9: int_e 10: int_m 11: int_j
// 12: dsum_p2g 13: cnt_p2g 14: dsum_g2p 15: cnt_g2p

__global__ __launch_bounds__(NT, 4) void fused_kernel(
    const float* __restrict__ pred, const float* __restrict__ gt,
    float* __restrict__ part)
{
    __shared__ uint64_t Mp[2][RH][8];    // pred mask, double-buffered
    __shared__ uint64_t Mg[2][RH][8];    // gt mask
    __shared__ float    EC[2][TH];       // pred colsums at cols 255|256
    __shared__ float    red[NW][16];

    // XCD-aware swizzle: 4 row-adjacent tiles share an XCD's L2
    int fid = blockIdx.x;
    int b   = fid >> 5;
    int t5  = fid & 31;
    int tile = ((t5 & 7) << 2) | (t5 >> 3);

    const float* pimg = pred + (size_t)b * H * W;
    const float* gimg = gt   + (size_t)b * H * W;
    int y0 = tile * TH;
    int tid = threadIdx.x, lane = tid & 63, wid = tid >> 6;

    // ---- Phase 1: ballot masks, rows y0-9 .. y0+24 (272 tasks, x2 unrolled)
    // stride 16 from wid<8: s <= 263, s+8 <= 271 < 272, covers all residues.
    for (int s = wid; s < RH * 8; s += 2 * NW) {
        int rA = s >> 3, segA = s & 7;
        int rB = (s + NW) >> 3, segB = (s + NW) & 7;
        int ryA = y0 - HALO + rA, ryB = y0 - HALO + rB;
        float vpA = 0.f, vgA = 0.f, vpB = 0.f, vgB = 0.f;
        if ((unsigned)ryA < (unsigned)H) {
            int idx = ryA * W + segA * 64 + lane;
            vpA = pimg[idx]; vgA = gimg[idx];
        }
        if ((unsigned)ryB < (unsigned)H) {
            int idx = ryB * W + segB * 64 + lane;
            vpB = pimg[idx]; vgB = gimg[idx];
        }
        unsigned long long mpA = __ballot(vpA > 0.5f);
        unsigned long long mgA = __ballot(vgA > 0.5f);
        unsigned long long mpB = __ballot(vpB > 0.5f);
        unsigned long long mgB = __ballot(vgB > 0.5f);
        if (lane == 0) {
            Mp[0][rA][segA] = mpA; Mg[0][rA][segA] = mgA;
            Mp[0][rB][segB] = mpB; Mg[0][rB][segB] = mgB;
        }
    }
    // pred edge colsums (cols 255,256) for the cross-wave stencil halo
    if (tid < 2 * TH) {
        int c = tid >> 4, r = tid & (TH - 1);
        int y = y0 + r, col = 255 + c;
        float sum = (y > 0     ? pimg[(size_t)(y - 1) * W + col] : 0.f)
                  +              pimg[(size_t)y * W + col]
                  + (y < H - 1 ? pimg[(size_t)(y + 1) * W + col] : 0.f);
        EC[c][r] = sum;
    }
    __syncthreads();

    // ---- Target bits for distance (center 16 rows = 128 words, tid<128)
    uint64_t Tp = 0ULL, Tg = 0ULL;
    if (tid < TH * 8) {
        int r = HALO + (tid >> 3), w = tid & 7;
        Tp = Mp[0][r][w]; Tg = Mg[0][r][w];
    }
    int dcnt_p = __popcll(Tp), dcnt_g = __popcll(Tg);
    int dsum_p = dcnt_p, dsum_g = dcnt_g;   // a=0 baseline (dist >= 1)

    // ---- Stencil + dice: pred via floats (rolling rows), gt via bit popcounts
    float v0 = 0.f, v1 = 0.f;
    float c3=0,c4=0,c5=0,c6=0,c7=0,c8=0,c9=0,c10=0,c11=0;
    {
        int qi = tid & 127, h = tid >> 7;     // h in 0..3, 4 rows each
        int x4 = qi * 4;
        int wdx = qi >> 4;                    // word for this quad
        int ss = (qi & 15) * 4;               // bit offset of x4 in word
        int ys = y0 + h * 4;

        auto win6 = [&](int rb) -> uint32_t {
            const uint64_t* row = Mg[0][rb];
            uint64_t bm = row[wdx];
            if (ss == 0) {
                uint64_t lo = wdx ? row[wdx - 1] : 0ULL;
                return (uint32_t)(((bm << 1) | (lo >> 63)) & 0x3FULL);
            }
            uint32_t v = (uint32_t)((bm >> (ss - 1)) & 0x3FULL);
            if (ss == 60) {
                uint64_t hi = (wdx < 7) ? row[wdx + 1] : 0ULL;
                v |= ((uint32_t)hi & 1u) << 5;
            }
            return v;
        };

        int rb0 = h * 4 + HALO - 1;           // bit-row of (ys-1)
        uint32_t wU = win6(rb0), wM = win6(rb0 + 1);

        float4 pm4, pc4;
        {
            bool hm = ys > 0;
            pm4 = hm ? *(const float4*)(pimg + (size_t)(ys - 1) * W + x4)
                     : make_float4(0, 0, 0, 0);
            pc4 = *(const float4*)(pimg + (size_t)ys * W + x4);
        }
        for (int r = 0; r < 4; ++r) {
            int y = ys + r;
            float4 pp4 = (y < H - 1) ? *(const float4*)(pimg + (size_t)(y + 1) * W + x4)
                                     : make_float4(0, 0, 0, 0);
            uint32_t wD = win6(rb0 + 2 + r);
            int ry = h * 4 + r;

            float ps[6];
            ps[1] = pm4.x + pc4.x + pp4.x; ps[2] = pm4.y + pc4.y + pp4.y;
            ps[3] = pm4.z + pc4.z + pp4.z; ps[4] = pm4.w + pc4.w + pp4.w;
            float psl = __shfl_up(ps[4], 1, 64);
            float psr = __shfl_down(ps[1], 1, 64);
            if (lane == 0)  psl = (qi == 0)   ? 0.f : EC[0][ry];
            if (lane == 63) psr = (qi == 127) ? 0.f : EC[1][ry];
            ps[0] = psl; ps[5] = psr;

            float pcv[4] = {pc4.x, pc4.y, pc4.z, pc4.w};
            #pragma unroll
            for (int j = 0; j < 4; ++j) {
                float np = ps[j] + ps[j + 1] + ps[j + 2] - pcv[j];
                bool pon = pcv[j] > 0.5f;
                bool pe  = pon && (np == 1.f);
                bool pmb = pon && (np == 2.f);
                bool pjb = pon && (np > 2.f);
                uint32_t n9 = ((wU >> j) & 7u) | (((wM >> j) & 7u) << 3) | (((wD >> j) & 7u) << 6);
                uint32_t cen = (wM >> (j + 1)) & 1u;
                int ng = __popc(n9) - (int)cen;
                bool gon = cen != 0u;
                bool ge  = gon && (ng == 1);
                bool gmb = gon && (ng == 2);
                bool gjb = gon && (ng > 2);
                v1 += pcv[j];
                v0 += gon ? pcv[j] : 0.f;
                c3 += pe;  c4 += pmb;  c5 += pjb;
                c6 += ge;  c7 += gmb;  c8 += gjb;
                c9  += (pe && ge);
                c10 += (pmb && gmb);
                c11 += (pjb && gjb);
            }
            pm4 = pc4; pc4 = pp4; wU = wM; wM = wD;
        }
    }

    // ---- 9 bit-dilation steps (272 active word-tasks); popcount after each
    int cur = 0;
    bool active = tid < RH * 8;
    int rr = tid >> 3, ww = tid & 7;
    int rc = HALO + (tid >> 3), wc = tid & 7;   // center word (tid < 128)
    for (int a = 1; a <= 9; ++a) {
        if (active) {
            uint64_t up, md, dn;
            up = rr ? Mp[cur][rr - 1][ww] : 0ULL;
            md = Mp[cur][rr][ww];
            dn = (rr < RH - 1) ? Mp[cur][rr + 1][ww] : 0ULL;
            uint64_t Xp = up | md | dn;
            up = rr ? Mg[cur][rr - 1][ww] : 0ULL;
            md = Mg[cur][rr][ww];
            dn = (rr < RH - 1) ? Mg[cur][rr + 1][ww] : 0ULL;
            uint64_t Xg = up | md | dn;

            uint32_t lmp = __shfl_up  ((uint32_t)(Xp >> 63), 1, 64);
            uint32_t rlp = __shfl_down((uint32_t)(Xp & 1ULL), 1, 64);
            uint32_t lmg = __shfl_up  ((uint32_t)(Xg >> 63), 1, 64);
            uint32_t rlg = __shfl_down((uint32_t)(Xg & 1ULL), 1, 64);

            uint64_t Yp = Xp | (Xp << 1) | (Xp >> 1);
            uint64_t Yg = Xg | (Xg << 1) | (Xg >> 1);
            if (ww > 0) { Yp |= (uint64_t)(lmp & 1u); Yg |= (uint64_t)(lmg & 1u); }
            if (ww < 7) { Yp |= ((uint64_t)(rlp & 1u)) << 63; Yg |= ((uint64_t)(rlg & 1u)) << 63; }
            Mp[cur ^ 1][rr][ww] = Yp;
            Mg[cur ^ 1][rr][ww] = Yg;
        }
        __syncthreads();
        cur ^= 1;
        if (tid < TH * 8) {
            dsum_p += __popcll(Tp & ~Mg[cur][rc][wc]);  // pred targets vs gt coverage
            dsum_g += __popcll(Tg & ~Mp[cur][rc][wc]);  // gt targets vs pred coverage
        }
    }

    // ---- Reductions -> per-block partials (no atomics)
    float vals[16];
    vals[0] = v0; vals[1] = v1; vals[2] = (float)dcnt_g;
    vals[3] = c3; vals[4] = c4; vals[5] = c5;
    vals[6] = c6; vals[7] = c7; vals[8] = c8;
    vals[9] = c9; vals[10] = c10; vals[11] = c11;
    vals[12] = (float)dsum_p; vals[13] = (float)dcnt_p;
    vals[14] = (float)dsum_g; vals[15] = (float)dcnt_g;
    #pragma unroll
    for (int j = 0; j < 16; ++j)
        #pragma unroll
        for (int off = 32; off; off >>= 1)
            vals[j] += __shfl_down(vals[j], off, 64);
    if (lane == 0) {
        #pragma unroll
        for (int j = 0; j < 16; ++j) red[wid][j] = vals[j];
    }
    __syncthreads();
    if (tid < 16) {
        float s = 0.f;
        #pragma unroll
        for (int wv = 0; wv < NW; ++wv) s += red[wv][tid];
        part[fid * NACC + tid] = s;
    }
}

// ---------------------------------------------------------------------------
// Final: reduce 1024x16 partials -> 32x16 -> scalar. One block, deterministic.
// ---------------------------------------------------------------------------
__global__ __launch_bounds__(512) void final_kernel(
    const float* __restrict__ part, float* __restrict__ out)
{
    __shared__ float sacc[BATCH][NACC];
    __shared__ float tri[BATCH][3];
    int t = threadIdx.x;
    {
        int b = t >> 4, k = t & 15;
        float s = 0.f;
        #pragma unroll 4
        for (int j = 0; j < NTILE; ++j)
            s += part[((b << 5) + j) * NACC + k];
        sacc[b][k] = s;
    }
    __syncthreads();
    if (t < BATCH) {
        const float* a = sacc[t];
        float inter = a[0], psum = a[1], gsum = a[2];
        float dice = (2.f * inter + 1.f) / (psum + gsum + 1.f);

        float pe = a[3], pm = a[4], pj = a[5];
        float ge = a[6], gm = a[7], gj = a[8];
        float ie = a[9], im = a[10], ij = a[11];
        float e_iou = (ie + 1.f) / (pe + ge - ie + 1.f);
        float m_iou = (im + 1.f) / (pm + gm - im + 1.f);
        float j_iou = (ij + 1.f) / (pj + gj - ij + 1.f);
        float total = ge + gj + gm + 1.f;
        float sloss = 1.f - ((ge / total) * e_iou + (gj / total) * j_iou + (gm / total) * m_iou);

        float p2g = a[12] / (a[13] + 1.f);
        float g2p = a[14] / (a[15] + 1.f);
        float med = ((p2g + g2p) * 0.5f) / 10.f;
        tri[t][0] = dice; tri[t][1] = sloss; tri[t][2] = med;
    }
    __syncthreads();
    if (t == 0) {
        float dice = 0.f, sloss = 0.f, med = 0.f;
        for (int b = 0; b < BATCH; ++b) {
            dice += tri[b][0]; sloss += tri[b][1]; med += tri[b][2];
        }
        float dice_loss  = 1.f - dice / (float)BATCH;
        float structural = sloss / (float)BATCH;
        float medial     = med / (float)BATCH;
        float avg = (dice_loss + structural + medial) / 3.f;
        float r = dice_loss  / (dice_loss  + 1.f) * avg
                + structural / (structural + 1.f) * avg
                + medial     / (medial     + 1.f) * avg;
        out[0] = r;
    }
}

extern "C" void kernel_launch(void* const* d_in, const int* in_sizes, int n_in,
                              void* d_out, int out_size, void* d_ws, size_t ws_size,
                              hipStream_t stream)
{
    const float* pred = (const float*)d_in[0];
    const float* gt   = (const float*)d_in[1];
    float* part = (float*)d_ws;
    float* out  = (float*)d_out;

    fused_kernel<<<dim3(NBLK), NT, 0, stream>>>(pred, gt, part);
    final_kernel<<<1, 512, 0, stream>>>(part, out);
}

// Round 7
// 137.141 us; speedup vs baseline: 2.5117x; 1.0169x over previous
//
#include <hip/hip_runtime.h>
#include <stdint.h>

#define BATCH 32
#define H 512
#define W 512
#define NACC 16
#define TH 32              // center rows per tile
#define HALO 9             // need M_1..M_9 only
#define RH (TH + 2*HALO)   // 50 rows incl. halo
#define NT 1024
#define NW (NT/64)         // 16 waves
#define NTILE (H/TH)       // 16
#define NBLK (NTILE*BATCH) // 512 blocks = 2/CU (full 32-wave occupancy)

// part[fid*NACC + k] per-block partials (no atomics, deterministic):
//  0: sum(p*g)  1: sum(p)  2: sum(g)
//  3: cnt_pe 4: cnt_pm 5: cnt_pj  6: cnt_ge 7: cnt_gm 8: cnt_gj
//  9: int_e 10: int_m 11: int_j
// 12: dsum_p2g 13: cnt_p2g 14: dsum_g2p 15: cnt_g2p

__global__ __launch_bounds__(NT, 8) void fused_kernel(
    const float* __restrict__ pred, const float* __restrict__ gt,
    float* __restrict__ part)
{
    __shared__ uint64_t Mp[2][RH][8];    // pred mask, double-buffered
    __shared__ uint64_t Mg[2][RH][8];    // gt mask
    __shared__ float    EC[2][TH];       // pred colsums at cols 255|256
    __shared__ float    red[NW][16];

    // XCD swizzle: tiles 2k,2k+1 come from fids congruent mod 8 (same XCD
    // under round-robin dispatch) so vertically-adjacent halos share L2.
    int fid = blockIdx.x;
    int b   = fid >> 4;
    int t4  = fid & 15;
    int tile = ((t4 & 7) << 1) | (t4 >> 3);

    const float* pimg = pred + (size_t)b * H * W;
    const float* gimg = gt   + (size_t)b * H * W;
    int y0 = tile * TH;
    int tid = threadIdx.x, lane = tid & 63, wid = tid >> 6;

    // ---- Phase 1: ballot masks, rows y0-9..y0+40 (400 word-tasks, x4 unroll,
    // 8 global loads in flight per wave iteration)
    for (int s0 = wid; s0 < RH * 8; s0 += 4 * NW) {
        float vp[4], vg[4];
        int   rr[4], sg[4];
        bool  ok[4];
        #pragma unroll
        for (int u = 0; u < 4; ++u) {
            int s = s0 + 16 * u;
            ok[u] = s < RH * 8;
            rr[u] = s >> 3; sg[u] = s & 7;
            vp[u] = 0.f; vg[u] = 0.f;
            int ry = y0 - HALO + rr[u];
            if (ok[u] && (unsigned)ry < (unsigned)H) {
                int idx = ry * W + sg[u] * 64 + lane;
                vp[u] = pimg[idx];
                vg[u] = gimg[idx];
            }
        }
        #pragma unroll
        for (int u = 0; u < 4; ++u) {
            if (ok[u]) {   // wave-uniform
                unsigned long long mp = __ballot(vp[u] > 0.5f);
                unsigned long long mg = __ballot(vg[u] > 0.5f);
                if (lane == 0) { Mp[0][rr[u]][sg[u]] = mp; Mg[0][rr[u]][sg[u]] = mg; }
            }
        }
    }
    // pred edge colsums (cols 255,256) for the cross-wave stencil halo
    if (tid < 2 * TH) {
        int c = tid >> 5, r = tid & (TH - 1);
        int y = y0 + r, col = 255 + c;
        float sum = (y > 0     ? pimg[(size_t)(y - 1) * W + col] : 0.f)
                  +              pimg[(size_t)y * W + col]
                  + (y < H - 1 ? pimg[(size_t)(y + 1) * W + col] : 0.f);
        EC[c][r] = sum;
    }
    __syncthreads();

    // ---- Target bits for distance (center 32 rows = 256 words, tid<256)
    uint64_t Tp = 0ULL, Tg = 0ULL;
    int rT = HALO + (tid >> 3), wT = tid & 7;
    if (tid < TH * 8) { Tp = Mp[0][rT][wT]; Tg = Mg[0][rT][wT]; }
    int dcnt_p = __popcll(Tp), dcnt_g = __popcll(Tg);
    int dsum_p = dcnt_p, dsum_g = dcnt_g;   // a=0 baseline (dist >= 1)

    // ---- Stencil + dice: pred via floats (rolling rows), gt via bit popcounts
    float v0 = 0.f, v1 = 0.f;
    float c3=0,c4=0,c5=0,c6=0,c7=0,c8=0,c9=0,c10=0,c11=0;
    {
        int qi = tid & 127, h = tid >> 7;     // h in 0..7, 4 rows each
        int x4 = qi * 4;
        int wdx = qi >> 4;                    // word for this quad
        int ss = (qi & 15) * 4;               // bit offset of x4 in word
        int ys = y0 + h * 4;

        auto win6 = [&](int rb) -> uint32_t {
            const uint64_t* row = Mg[0][rb];
            uint64_t bm = row[wdx];
            if (ss == 0) {
                uint64_t lo = wdx ? row[wdx - 1] : 0ULL;
                return (uint32_t)(((bm << 1) | (lo >> 63)) & 0x3FULL);
            }
            uint32_t v = (uint32_t)((bm >> (ss - 1)) & 0x3FULL);
            if (ss == 60) {
                uint64_t hi = (wdx < 7) ? row[wdx + 1] : 0ULL;
                v |= ((uint32_t)hi & 1u) << 5;
            }
            return v;
        };

        int rb0 = h * 4 + HALO - 1;           // bit-row of (ys-1)
        uint32_t wU = win6(rb0), wM = win6(rb0 + 1);

        float4 pm4, pc4;
        {
            bool hm = ys > 0;
            pm4 = hm ? *(const float4*)(pimg + (size_t)(ys - 1) * W + x4)
                     : make_float4(0, 0, 0, 0);
            pc4 = *(const float4*)(pimg + (size_t)ys * W + x4);
        }
        for (int r = 0; r < 4; ++r) {
            int y = ys + r;
            float4 pp4 = (y < H - 1) ? *(const float4*)(pimg + (size_t)(y + 1) * W + x4)
                                     : make_float4(0, 0, 0, 0);
            uint32_t wD = win6(rb0 + 2 + r);
            int ry = h * 4 + r;

            float ps[6];
            ps[1] = pm4.x + pc4.x + pp4.x; ps[2] = pm4.y + pc4.y + pp4.y;
            ps[3] = pm4.z + pc4.z + pp4.z; ps[4] = pm4.w + pc4.w + pp4.w;
            float psl = __shfl_up(ps[4], 1, 64);
            float psr = __shfl_down(ps[1], 1, 64);
            if (lane == 0)  psl = (qi == 0)   ? 0.f : EC[0][ry];
            if (lane == 63) psr = (qi == 127) ? 0.f : EC[1][ry];
            ps[0] = psl; ps[5] = psr;

            float pcv[4] = {pc4.x, pc4.y, pc4.z, pc4.w};
            #pragma unroll
            for (int j = 0; j < 4; ++j) {
                float np = ps[j] + ps[j + 1] + ps[j + 2] - pcv[j];
                bool pon = pcv[j] > 0.5f;
                bool pe  = pon && (np == 1.f);
                bool pmb = pon && (np == 2.f);
                bool pjb = pon && (np > 2.f);
                uint32_t n9 = ((wU >> j) & 7u) | (((wM >> j) & 7u) << 3) | (((wD >> j) & 7u) << 6);
                uint32_t cen = (wM >> (j + 1)) & 1u;
                int ng = __popc(n9) - (int)cen;
                bool gon = cen != 0u;
                bool ge  = gon && (ng == 1);
                bool gmb = gon && (ng == 2);
                bool gjb = gon && (ng > 2);
                v1 += pcv[j];
                v0 += gon ? pcv[j] : 0.f;
                c3 += pe;  c4 += pmb;  c5 += pjb;
                c6 += ge;  c7 += gmb;  c8 += gjb;
                c9  += (pe && ge);
                c10 += (pmb && gmb);
                c11 += (pjb && gjb);
            }
            pm4 = pc4; pc4 = pp4; wU = wM; wM = wD;
        }
    }

    // ---- 9 bit-dilation steps: p/g split across thread halves, shrinking
    // active rows (step a only needs rows [a, 49-a]); popcount after each.
    int cur = 0;
    int half = tid >> 9;           // 0: pred mask, 1: gt mask
    int t    = tid & 511;
    for (int a = 1; a <= 9; ++a) {
        int ntask = (RH - 2 * a) * 8;        // 384..256, multiple of 16
        if (t < ntask) {                     // intra-wave divergence only at
            int r = a + (t >> 3), w = t & 7; // multiples of 16 — shfl sources
            uint64_t (*Msrc)[8] = half ? Mg[cur] : Mp[cur];          // always active
            uint64_t (*Mdst)[8] = half ? Mg[cur ^ 1] : Mp[cur ^ 1];
            uint64_t X = Msrc[r - 1][w] | Msrc[r][w] | Msrc[r + 1][w];
            uint32_t lm = __shfl_up  ((uint32_t)(X >> 63), 1, 64);
            uint32_t rl = __shfl_down((uint32_t)(X & 1ULL), 1, 64);
            uint64_t Y = X | (X << 1) | (X >> 1);
            if (w > 0) Y |= (uint64_t)(lm & 1u);
            if (w < 7) Y |= ((uint64_t)(rl & 1u)) << 63;
            Mdst[r][w] = Y;
        }
        __syncthreads();
        cur ^= 1;
        if (tid < TH * 8) {
            dsum_p += __popcll(Tp & ~Mg[cur][rT][wT]);  // pred targets vs gt coverage
            dsum_g += __popcll(Tg & ~Mp[cur][rT][wT]);  // gt targets vs pred coverage
        }
    }

    // ---- Reductions -> per-block partials (no atomics)
    float vals[16];
    vals[0] = v0; vals[1] = v1; vals[2] = (float)dcnt_g;
    vals[3] = c3; vals[4] = c4; vals[5] = c5;
    vals[6] = c6; vals[7] = c7; vals[8] = c8;
    vals[9] = c9; vals[10] = c10; vals[11] = c11;
    vals[12] = (float)dsum_p; vals[13] = (float)dcnt_p;
    vals[14] = (float)dsum_g; vals[15] = (float)dcnt_g;
    #pragma unroll
    for (int j = 0; j < 16; ++j)
        #pragma unroll
        for (int off = 32; off; off >>= 1)
            vals[j] += __shfl_down(vals[j], off, 64);
    if (lane == 0) {
        #pragma unroll
        for (int j = 0; j < 16; ++j) red[wid][j] = vals[j];
    }
    __syncthreads();
    if (tid < 16) {
        float s = 0.f;
        #pragma unroll
        for (int wv = 0; wv < NW; ++wv) s += red[wv][tid];
        part[fid * NACC + tid] = s;
    }
}

// ---------------------------------------------------------------------------
// Final: reduce 512x16 partials -> 32x16 -> scalar. One block, deterministic.
// ---------------------------------------------------------------------------
__global__ __launch_bounds__(512) void final_kernel(
    const float* __restrict__ part, float* __restrict__ out)
{
    __shared__ float sacc[BATCH][NACC];
    __shared__ float tri[BATCH][3];
    int t = threadIdx.x;
    {
        int b = t >> 4, k = t & 15;
        float s = 0.f;
        #pragma unroll 4
        for (int j = 0; j < NTILE; ++j)
            s += part[((b << 4) + j) * NACC + k];
        sacc[b][k] = s;
    }
    __syncthreads();
    if (t < BATCH) {
        const float* a = sacc[t];
        float inter = a[0], psum = a[1], gsum = a[2];
        float dice = (2.f * inter + 1.f) / (psum + gsum + 1.f);

        float pe = a[3], pm = a[4], pj = a[5];
        float ge = a[6], gm = a[7], gj = a[8];
        float ie = a[9], im = a[10], ij = a[11];
        float e_iou = (ie + 1.f) / (pe + ge - ie + 1.f);
        float m_iou = (im + 1.f) / (pm + gm - im + 1.f);
        float j_iou = (ij + 1.f) / (pj + gj - ij + 1.f);
        float total = ge + gj + gm + 1.f;
        float sloss = 1.f - ((ge / total) * e_iou + (gj / total) * j_iou + (gm / total) * m_iou);

        float p2g = a[12] / (a[13] + 1.f);
        float g2p = a[14] / (a[15] + 1.f);
        float med = ((p2g + g2p) * 0.5f) / 10.f;
        tri[t][0] = dice; tri[t][1] = sloss; tri[t][2] = med;
    }
    __syncthreads();
    if (t == 0) {
        float dice = 0.f, sloss = 0.f, med = 0.f;
        for (int b = 0; b < BATCH; ++b) {
            dice += tri[b][0]; sloss += tri[b][1]; med += tri[b][2];
        }
        float dice_loss  = 1.f - dice / (float)BATCH;
        float structural = sloss / (float)BATCH;
        float medial     = med / (float)BATCH;
        float avg = (dice_loss + structural + medial) / 3.f;
        float r = dice_loss  / (dice_loss  + 1.f) * avg
                + structural / (structural + 1.f) * avg
                + medial     / (medial     + 1.f) * avg;
        out[0] = r;
    }
}

extern "C" void kernel_launch(void* const* d_in, const int* in_sizes, int n_in,
                              void* d_out, int out_size, void* d_ws, size_t ws_size,
                              hipStream_t stream)
{
    const float* pred = (const float*)d_in[0];
    const float* gt   = (const float*)d_in[1];
    float* part = (float*)d_ws;
    float* out  = (float*)d_out;

    fused_kernel<<<dim3(NBLK), NT, 0, stream>>>(pred, gt, part);
    final_kernel<<<1, 512, 0, stream>>>(part, out);
}